// Round 1
// baseline (290.085 us; speedup 1.0000x reference)
//
#include <hip/hip_runtime.h>
#include <hip/hip_bf16.h>

#define Hh    128
#define NINc  384
#define KN    48
#define FFd   512
#define NNODE 8192

typedef __attribute__((ext_vector_type(8))) short short8v;
typedef __attribute__((ext_vector_type(4))) float f32x4;

__device__ __forceinline__ short f2bf(float f){
  union { float f; unsigned u; } v; v.f = f;
  unsigned r = v.u + 0x7FFFu + ((v.u >> 16) & 1u);
  return (short)(r >> 16);
}

// exact identity: 0.5x(1+tanh(t)) == x*sigmoid(2t); tanh-form GELU, max dev from erf-GELU ~3e-4
__device__ __forceinline__ float gelu_f(float x){
  float t = 0.7978845608028654f * x * (1.0f + 0.044715f * x * x);
  float e = __expf(2.0f * t);           // inf-safe
  return x * (1.0f - 1.0f / (e + 1.0f));
}

// ---------------- weight prep: transpose to [out][in], convert to bf16 ----------------
__global__ void prep_weights(const float* __restrict__ W1, const float* __restrict__ W2,
                             const float* __restrict__ W3, const float* __restrict__ Win,
                             const float* __restrict__ Wout,
                             short* __restrict__ w1vT, short* __restrict__ w1eT,
                             short* __restrict__ w2T,  short* __restrict__ w3T,
                             short* __restrict__ winT, short* __restrict__ woutT)
{
  int i = blockIdx.x * 256 + threadIdx.x;
  if (i < 16384){ int n = i / 128, k = i % 128; w1vT[i] = f2bf(W1[k*128 + n]); return; }
  i -= 16384;
  if (i < 49152){ int n = i / 384, k = i % 384; w1eT[i] = f2bf(W1[(128+k)*128 + n]); return; }
  i -= 49152;
  if (i < 16384){ int n = i / 128, k = i % 128; w2T[i] = f2bf(W2[k*128 + n]); return; }
  i -= 16384;
  if (i < 16384){ int n = i / 128, k = i % 128; w3T[i] = f2bf(W3[k*128 + n]); return; }
  i -= 16384;
  if (i < 65536){ int n = i / 128, k = i % 128; winT[i] = f2bf(Win[k*512 + n]); return; }
  i -= 65536;
  if (i < 65536){ int n = i / 512, k = i % 512; woutT[i] = f2bf(Wout[k*128 + n]); return; }
}

// ---------------- node_part = h_V @ W1[:128,:] + b1  (tiny MFMA GEMM) ----------------
__global__ __launch_bounds__(256,2) void np_kernel(
    const float* __restrict__ hV, const short* __restrict__ w1vT,
    const float* __restrict__ b1, float* __restrict__ npart)
{
  const int row0 = blockIdx.x * 64;
  const int tid = threadIdx.x, lane = tid & 63, wv = tid >> 6;
  __shared__ __attribute__((aligned(16))) short Xs[64][Hh + 8];

  const float4* src = (const float4*)(hV + (size_t)row0 * Hh);
  #pragma unroll
  for (int j = 0; j < 8; ++j){
    int idx = tid + 256*j;           // < 2048
    int r = idx >> 5, c4 = idx & 31;
    float4 v = src[idx];
    short4 s = make_short4(f2bf(v.x), f2bf(v.y), f2bf(v.z), f2bf(v.w));
    *(short4*)&Xs[r][c4*4] = s;
  }
  __syncthreads();

  const int arow = lane & 15, kgrp = (lane >> 4) * 8;
  const int col0 = wv * 32, ccol = lane & 15, crow0 = (lane >> 4) * 4;

  f32x4 acc[4][2];
  #pragma unroll
  for (int m = 0; m < 4; ++m) for (int n = 0; n < 2; ++n) acc[m][n] = (f32x4){0.f,0.f,0.f,0.f};

  const short8v* Bw = (const short8v*)w1vT;   // row stride 128/8 = 16
  #pragma unroll
  for (int ks = 0; ks < 4; ++ks){
    int kb = ks*32 + kgrp;
    short8v b0 = Bw[(col0 + arow)*16      + (kb >> 3)];
    short8v b1f = Bw[(col0 + 16 + arow)*16 + (kb >> 3)];
    #pragma unroll
    for (int m = 0; m < 4; ++m){
      short8v a = *(const short8v*)&Xs[m*16 + arow][kb];
      acc[m][0] = __builtin_amdgcn_mfma_f32_16x16x32_bf16(a, b0,  acc[m][0], 0,0,0);
      acc[m][1] = __builtin_amdgcn_mfma_f32_16x16x32_bf16(a, b1f, acc[m][1], 0,0,0);
    }
  }
  #pragma unroll
  for (int m = 0; m < 4; ++m) for (int n = 0; n < 2; ++n){
    int colg = col0 + n*16 + ccol;
    float bb = b1[colg];
    #pragma unroll
    for (int r = 0; r < 4; ++r)
      npart[(size_t)(row0 + m*16 + crow0 + r)*Hh + colg] = acc[m][n][r] + bb;
  }
}

// ---------------- per-node edge MLP + masked K-sum + residual ----------------
__global__ __launch_bounds__(256,2) void edge_kernel(
    const float* __restrict__ hE, const float* __restrict__ hV,
    const float* __restrict__ maskA, const float* __restrict__ npart,
    const short* __restrict__ w1eT, const short* __restrict__ w2T,
    const short* __restrict__ w3T,
    const float* __restrict__ b2, const float* __restrict__ b3,
    float* __restrict__ out)
{
  const int node = blockIdx.x;
  const int tid = threadIdx.x, lane = tid & 63, wv = tid >> 6;

  __shared__ __attribute__((aligned(16))) short Et[KN][NINc + 8];
  __shared__ __attribute__((aligned(16))) short M1[KN][Hh + 8];
  __shared__ __attribute__((aligned(16))) short M2[KN][Hh + 8];
  __shared__ float msk[KN];
  __shared__ float npS[Hh], b2S[Hh], b3S[Hh], hvS[Hh];
  __shared__ float smaskSum;

  // stage h_E tile (48x384 f32 -> bf16), coalesced float4
  {
    const float4* src = (const float4*)(hE + (size_t)node * (KN*NINc));
    #pragma unroll
    for (int j = 0; j < 18; ++j){
      int idx = tid + 256*j;          // < 4608
      int r = idx / 96, c4 = idx - r*96;
      float4 v = src[idx];
      short4 s = make_short4(f2bf(v.x), f2bf(v.y), f2bf(v.z), f2bf(v.w));
      *(short4*)&Et[r][c4*4] = s;
    }
  }
  if (tid < KN) msk[tid] = maskA[node*KN + tid];
  if (tid < Hh){
    npS[tid] = npart[(size_t)node*Hh + tid];
    b2S[tid] = b2[tid];
    b3S[tid] = b3[tid];
    hvS[tid] = hV[(size_t)node*Hh + tid];
  }
  __syncthreads();
  if (tid == 0){ float s = 0.f; for (int k = 0; k < KN; ++k) s += msk[k]; smaskSum = s; }

  const int arow = lane & 15, kgrp = (lane >> 4) * 8;
  const int col0 = wv * 32, ccol = lane & 15, crow0 = (lane >> 4) * 4;

  // ---- GEMM1: Et[48x384] @ W1e^T -> gelu(+node_part) -> M1 ----
  {
    f32x4 acc[3][2];
    #pragma unroll
    for (int m = 0; m < 3; ++m) for (int n = 0; n < 2; ++n) acc[m][n] = (f32x4){0.f,0.f,0.f,0.f};
    const short8v* B1 = (const short8v*)w1eT;   // row stride 384/8 = 48
    #pragma unroll
    for (int ks = 0; ks < 12; ++ks){
      int kb = ks*32 + kgrp;
      short8v b0 = B1[(col0 + arow)*48      + (kb >> 3)];
      short8v b1f = B1[(col0 + 16 + arow)*48 + (kb >> 3)];
      short8v a0 = *(const short8v*)&Et[arow][kb];
      short8v a1 = *(const short8v*)&Et[16 + arow][kb];
      short8v a2 = *(const short8v*)&Et[32 + arow][kb];
      acc[0][0] = __builtin_amdgcn_mfma_f32_16x16x32_bf16(a0,b0, acc[0][0],0,0,0);
      acc[1][0] = __builtin_amdgcn_mfma_f32_16x16x32_bf16(a1,b0, acc[1][0],0,0,0);
      acc[2][0] = __builtin_amdgcn_mfma_f32_16x16x32_bf16(a2,b0, acc[2][0],0,0,0);
      acc[0][1] = __builtin_amdgcn_mfma_f32_16x16x32_bf16(a0,b1f,acc[0][1],0,0,0);
      acc[1][1] = __builtin_amdgcn_mfma_f32_16x16x32_bf16(a1,b1f,acc[1][1],0,0,0);
      acc[2][1] = __builtin_amdgcn_mfma_f32_16x16x32_bf16(a2,b1f,acc[2][1],0,0,0);
    }
    #pragma unroll
    for (int m = 0; m < 3; ++m) for (int n = 0; n < 2; ++n){
      int colg = col0 + n*16 + ccol;
      float npv = npS[colg];
      #pragma unroll
      for (int r = 0; r < 4; ++r)
        M1[m*16 + crow0 + r][colg] = f2bf(gelu_f(acc[m][n][r] + npv));
    }
  }
  __syncthreads();

  // ---- GEMM2: M1 @ W2^T -> gelu(+b2) -> M2 ----
  {
    f32x4 acc[3][2];
    #pragma unroll
    for (int m = 0; m < 3; ++m) for (int n = 0; n < 2; ++n) acc[m][n] = (f32x4){0.f,0.f,0.f,0.f};
    const short8v* B2 = (const short8v*)w2T;    // row stride 16
    #pragma unroll
    for (int ks = 0; ks < 4; ++ks){
      int kb = ks*32 + kgrp;
      short8v b0 = B2[(col0 + arow)*16      + (kb >> 3)];
      short8v b1f = B2[(col0 + 16 + arow)*16 + (kb >> 3)];
      short8v a0 = *(const short8v*)&M1[arow][kb];
      short8v a1 = *(const short8v*)&M1[16 + arow][kb];
      short8v a2 = *(const short8v*)&M1[32 + arow][kb];
      acc[0][0] = __builtin_amdgcn_mfma_f32_16x16x32_bf16(a0,b0, acc[0][0],0,0,0);
      acc[1][0] = __builtin_amdgcn_mfma_f32_16x16x32_bf16(a1,b0, acc[1][0],0,0,0);
      acc[2][0] = __builtin_amdgcn_mfma_f32_16x16x32_bf16(a2,b0, acc[2][0],0,0,0);
      acc[0][1] = __builtin_amdgcn_mfma_f32_16x16x32_bf16(a0,b1f,acc[0][1],0,0,0);
      acc[1][1] = __builtin_amdgcn_mfma_f32_16x16x32_bf16(a1,b1f,acc[1][1],0,0,0);
      acc[2][1] = __builtin_amdgcn_mfma_f32_16x16x32_bf16(a2,b1f,acc[2][1],0,0,0);
    }
    #pragma unroll
    for (int m = 0; m < 3; ++m) for (int n = 0; n < 2; ++n){
      int colg = col0 + n*16 + ccol;
      float bb = b2S[colg];
      #pragma unroll
      for (int r = 0; r < 4; ++r)
        M2[m*16 + crow0 + r][colg] = f2bf(gelu_f(acc[m][n][r] + bb));
    }
  }
  __syncthreads();

  // ---- GEMM3: M2 @ W3^T, then masked sum over K rows ----
  {
    f32x4 acc[3][2];
    #pragma unroll
    for (int m = 0; m < 3; ++m) for (int n = 0; n < 2; ++n) acc[m][n] = (f32x4){0.f,0.f,0.f,0.f};
    const short8v* B3 = (const short8v*)w3T;
    #pragma unroll
    for (int ks = 0; ks < 4; ++ks){
      int kb = ks*32 + kgrp;
      short8v b0 = B3[(col0 + arow)*16      + (kb >> 3)];
      short8v b1f = B3[(col0 + 16 + arow)*16 + (kb >> 3)];
      short8v a0 = *(const short8v*)&M2[arow][kb];
      short8v a1 = *(const short8v*)&M2[16 + arow][kb];
      short8v a2 = *(const short8v*)&M2[32 + arow][kb];
      acc[0][0] = __builtin_amdgcn_mfma_f32_16x16x32_bf16(a0,b0, acc[0][0],0,0,0);
      acc[1][0] = __builtin_amdgcn_mfma_f32_16x16x32_bf16(a1,b0, acc[1][0],0,0,0);
      acc[2][0] = __builtin_amdgcn_mfma_f32_16x16x32_bf16(a2,b0, acc[2][0],0,0,0);
      acc[0][1] = __builtin_amdgcn_mfma_f32_16x16x32_bf16(a0,b1f,acc[0][1],0,0,0);
      acc[1][1] = __builtin_amdgcn_mfma_f32_16x16x32_bf16(a1,b1f,acc[1][1],0,0,0);
      acc[2][1] = __builtin_amdgcn_mfma_f32_16x16x32_bf16(a2,b1f,acc[2][1],0,0,0);
    }
    // masked column sums: bias handled as b3*sum(mask); each wave owns disjoint cols
    #pragma unroll
    for (int n = 0; n < 2; ++n){
      float s = 0.f;
      #pragma unroll
      for (int m = 0; m < 3; ++m)
        #pragma unroll
        for (int r = 0; r < 4; ++r)
          s += acc[m][n][r] * msk[m*16 + crow0 + r];
      s += __shfl_xor(s, 16);
      s += __shfl_xor(s, 32);
      if (lane < 16){
        int colg = col0 + n*16 + ccol;
        float dh = (s + b3S[colg] * smaskSum) * (1.0f/30.0f);
        out[(size_t)node*Hh + colg] = hvS[colg] + dh;
      }
    }
  }
}

// ---------------- batched LN1 -> FFN -> LN2 -> mask (in-place on d_out) ----------------
__global__ __launch_bounds__(256,2) void ffn_kernel(
    const float* __restrict__ ln1g, const float* __restrict__ ln1b,
    const short* __restrict__ winT, const float* __restrict__ bin,
    const short* __restrict__ woutT, const float* __restrict__ bout,
    const float* __restrict__ ln2g, const float* __restrict__ ln2b,
    const float* __restrict__ maskV, float* __restrict__ io)
{
  const int row0 = blockIdx.x * 32;
  const int tid = threadIdx.x, lane = tid & 63, wv = tid >> 6;
  __shared__ __attribute__((aligned(16))) short Xs[32][Hh + 8];
  __shared__ __attribute__((aligned(16))) float Rs[32][Hh + 4];
  __shared__ __attribute__((aligned(16))) short Hs[32][FFd + 8];

  const int arow = lane & 15, kgrp = (lane >> 4) * 8;
  const int ccol = lane & 15, crow0 = (lane >> 4) * 4;

  // ---- LN1 (8 lanes per row) ----
  {
    int r = tid >> 3, cb = (tid & 7) * 16;
    const float4* xp = (const float4*)(io + (size_t)(row0 + r)*Hh + cb);
    float xv[16];
    #pragma unroll
    for (int j = 0; j < 4; ++j){
      float4 v = xp[j];
      xv[j*4+0]=v.x; xv[j*4+1]=v.y; xv[j*4+2]=v.z; xv[j*4+3]=v.w;
    }
    float sum = 0.f, sq = 0.f;
    #pragma unroll
    for (int j = 0; j < 16; ++j){ sum += xv[j]; sq += xv[j]*xv[j]; }
    #pragma unroll
    for (int d = 1; d < 8; d <<= 1){ sum += __shfl_xor(sum, d); sq += __shfl_xor(sq, d); }
    float mu = sum * (1.0f/128.0f);
    float var = sq * (1.0f/128.0f) - mu*mu;
    float rstd = rsqrtf(var + 1e-5f);
    #pragma unroll
    for (int j = 0; j < 16; ++j){
      int c = cb + j;
      float xn = (xv[j] - mu) * rstd * ln1g[c] + ln1b[c];
      Xs[r][c] = f2bf(xn);
      Rs[r][c] = xn;          // residual = LN1 output
    }
  }
  __syncthreads();

  // ---- GEMM-in: [32x128] @ WinT -> gelu -> Hs[32x512] ----
  {
    f32x4 acc[2][8];
    #pragma unroll
    for (int m = 0; m < 2; ++m) for (int n = 0; n < 8; ++n) acc[m][n] = (f32x4){0.f,0.f,0.f,0.f};
    const short8v* Bw = (const short8v*)winT;   // row stride 16
    #pragma unroll
    for (int ks = 0; ks < 4; ++ks){
      int kb = ks*32 + kgrp;
      short8v a0 = *(const short8v*)&Xs[arow][kb];
      short8v a1 = *(const short8v*)&Xs[16 + arow][kb];
      #pragma unroll
      for (int n = 0; n < 8; ++n){
        short8v b = Bw[(wv*128 + n*16 + arow)*16 + (kb >> 3)];
        acc[0][n] = __builtin_amdgcn_mfma_f32_16x16x32_bf16(a0,b,acc[0][n],0,0,0);
        acc[1][n] = __builtin_amdgcn_mfma_f32_16x16x32_bf16(a1,b,acc[1][n],0,0,0);
      }
    }
    #pragma unroll
    for (int m = 0; m < 2; ++m) for (int n = 0; n < 8; ++n){
      int colg = wv*128 + n*16 + ccol;
      float bb = bin[colg];
      #pragma unroll
      for (int r = 0; r < 4; ++r)
        Hs[m*16 + crow0 + r][colg] = f2bf(gelu_f(acc[m][n][r] + bb));
    }
  }
  __syncthreads();

  // ---- GEMM-out: [32x512] @ WoutT -> + bout + resid -> Rs (pre-LN2) ----
  {
    f32x4 acc[2][2];
    #pragma unroll
    for (int m = 0; m < 2; ++m) for (int n = 0; n < 2; ++n) acc[m][n] = (f32x4){0.f,0.f,0.f,0.f};
    const short8v* Bw = (const short8v*)woutT;  // row stride 512/8 = 64
    #pragma unroll
    for (int ks = 0; ks < 16; ++ks){
      int kb = ks*32 + kgrp;
      short8v a0 = *(const short8v*)&Hs[arow][kb];
      short8v a1 = *(const short8v*)&Hs[16 + arow][kb];
      short8v b0 = Bw[(wv*32 + arow)*64      + (kb >> 3)];
      short8v b1f = Bw[(wv*32 + 16 + arow)*64 + (kb >> 3)];
      acc[0][0] = __builtin_amdgcn_mfma_f32_16x16x32_bf16(a0,b0, acc[0][0],0,0,0);
      acc[1][0] = __builtin_amdgcn_mfma_f32_16x16x32_bf16(a1,b0, acc[1][0],0,0,0);
      acc[0][1] = __builtin_amdgcn_mfma_f32_16x16x32_bf16(a0,b1f,acc[0][1],0,0,0);
      acc[1][1] = __builtin_amdgcn_mfma_f32_16x16x32_bf16(a1,b1f,acc[1][1],0,0,0);
    }
    #pragma unroll
    for (int m = 0; m < 2; ++m) for (int n = 0; n < 2; ++n){
      int colg = wv*32 + n*16 + ccol;
      float bb = bout[colg];
      #pragma unroll
      for (int r = 0; r < 4; ++r){
        int rr = m*16 + crow0 + r;
        Rs[rr][colg] = Rs[rr][colg] + acc[m][n][r] + bb;
      }
    }
  }
  __syncthreads();

  // ---- LN2 + mask + store ----
  {
    int r = tid >> 3, cb = (tid & 7) * 16;
    float xv[16];
    #pragma unroll
    for (int j = 0; j < 16; ++j) xv[j] = Rs[r][cb + j];
    float sum = 0.f, sq = 0.f;
    #pragma unroll
    for (int j = 0; j < 16; ++j){ sum += xv[j]; sq += xv[j]*xv[j]; }
    #pragma unroll
    for (int d = 1; d < 8; d <<= 1){ sum += __shfl_xor(sum, d); sq += __shfl_xor(sq, d); }
    float mu = sum * (1.0f/128.0f);
    float var = sq * (1.0f/128.0f) - mu*mu;
    float rstd = rsqrtf(var + 1e-5f);
    float mv = maskV[row0 + r];
    float* op = io + (size_t)(row0 + r)*Hh + cb;
    #pragma unroll
    for (int j = 0; j < 4; ++j){
      float4 o;
      o.x = ((xv[j*4+0] - mu)*rstd*ln2g[cb+j*4+0] + ln2b[cb+j*4+0]) * mv;
      o.y = ((xv[j*4+1] - mu)*rstd*ln2g[cb+j*4+1] + ln2b[cb+j*4+1]) * mv;
      o.z = ((xv[j*4+2] - mu)*rstd*ln2g[cb+j*4+2] + ln2b[cb+j*4+2]) * mv;
      o.w = ((xv[j*4+3] - mu)*rstd*ln2g[cb+j*4+3] + ln2b[cb+j*4+3]) * mv;
      ((float4*)op)[j] = o;
    }
  }
}

extern "C" void kernel_launch(void* const* d_in, const int* in_sizes, int n_in,
                              void* d_out, int out_size, void* d_ws, size_t ws_size,
                              hipStream_t stream)
{
  const float* hV    = (const float*)d_in[0];
  const float* hE    = (const float*)d_in[1];
  const float* maskV = (const float*)d_in[2];
  const float* maskA = (const float*)d_in[3];
  const float* W1w   = (const float*)d_in[4];
  const float* W1b   = (const float*)d_in[5];
  const float* W2w   = (const float*)d_in[6];
  const float* W2b   = (const float*)d_in[7];
  const float* W3w   = (const float*)d_in[8];
  const float* W3b   = (const float*)d_in[9];
  const float* Winw  = (const float*)d_in[10];
  const float* Winb  = (const float*)d_in[11];
  const float* Woutw = (const float*)d_in[12];
  const float* Woutb = (const float*)d_in[13];
  const float* l1g   = (const float*)d_in[14];
  const float* l1b   = (const float*)d_in[15];
  const float* l2g   = (const float*)d_in[16];
  const float* l2b   = (const float*)d_in[17];

  char* ws = (char*)d_ws;
  size_t off = 0;
  float* npart = (float*)(ws + off); off += (size_t)NNODE * Hh * 4;
  short* w1vT  = (short*)(ws + off); off += 128*128*2;
  short* w1eT  = (short*)(ws + off); off += 128*384*2;
  short* w2T   = (short*)(ws + off); off += 128*128*2;
  short* w3T   = (short*)(ws + off); off += 128*128*2;
  short* winT  = (short*)(ws + off); off += 512*128*2;
  short* woutT = (short*)(ws + off); off += 128*512*2;
  if (ws_size < off) return;   // loud failure (output stays poisoned) rather than corruption

  prep_weights<<<896, 256, 0, stream>>>(W1w, W2w, W3w, Winw, Woutw,
                                        w1vT, w1eT, w2T, w3T, winT, woutT);
  np_kernel<<<NNODE/64, 256, 0, stream>>>(hV, w1vT, W1b, npart);
  edge_kernel<<<NNODE, 256, 0, stream>>>(hE, hV, maskA, npart,
                                         w1eT, w2T, w3T, W2b, W3b, (float*)d_out);
  ffn_kernel<<<NNODE/32, 256, 0, stream>>>(l1g, l1b, winT, Winb, woutT, Woutb,
                                           l2g, l2b, maskV, (float*)d_out);
}

// Round 2
// 250.627 us; speedup vs baseline: 1.1574x; 1.1574x over previous
//
#include <hip/hip_runtime.h>
#include <hip/hip_bf16.h>

#define Hh    128
#define NINc  384
#define KN    48
#define FFd   512
#define NNODE 8192

typedef __attribute__((ext_vector_type(8))) short short8v;
typedef __attribute__((ext_vector_type(4))) float f32x4;

__device__ __forceinline__ short f2bf(float f){
  union { float f; unsigned u; } v; v.f = f;
  unsigned r = v.u + 0x7FFFu + ((v.u >> 16) & 1u);
  return (short)(r >> 16);
}

// 0.5x(1+tanh(t)) == x*sigmoid(2t); tanh-form GELU, max dev from erf-GELU ~3e-4
__device__ __forceinline__ float gelu_f(float x){
  float t = 0.7978845608028654f * x * (1.0f + 0.044715f * x * x);
  float e = __expf(2.0f * t);           // inf-safe
  return x * (1.0f - 1.0f / (e + 1.0f));
}

// ---------------- weight prep: transpose to [out][in], convert to bf16 ----------------
__global__ void prep_weights(const float* __restrict__ W1, const float* __restrict__ W2,
                             const float* __restrict__ W3, const float* __restrict__ Win,
                             const float* __restrict__ Wout,
                             short* __restrict__ w1vT, short* __restrict__ w1eT,
                             short* __restrict__ w2T,  short* __restrict__ w3T,
                             short* __restrict__ winT, short* __restrict__ woutT)
{
  int i = blockIdx.x * 256 + threadIdx.x;
  if (i < 16384){ int n = i / 128, k = i % 128; w1vT[i] = f2bf(W1[k*128 + n]); return; }
  i -= 16384;
  if (i < 49152){ int n = i / 384, k = i % 384; w1eT[i] = f2bf(W1[(128+k)*128 + n]); return; }
  i -= 49152;
  if (i < 16384){ int n = i / 128, k = i % 128; w2T[i] = f2bf(W2[k*128 + n]); return; }
  i -= 16384;
  if (i < 16384){ int n = i / 128, k = i % 128; w3T[i] = f2bf(W3[k*128 + n]); return; }
  i -= 16384;
  if (i < 65536){ int n = i / 128, k = i % 128; winT[i] = f2bf(Win[k*512 + n]); return; }
  i -= 65536;
  if (i < 65536){ int n = i / 512, k = i % 512; woutT[i] = f2bf(Wout[k*128 + n]); return; }
}

// ---------------- node_part = h_V @ W1[:128,:] + b1  (tiny MFMA GEMM) ----------------
__global__ __launch_bounds__(256,2) void np_kernel(
    const float* __restrict__ hV, const short* __restrict__ w1vT,
    const float* __restrict__ b1, float* __restrict__ npart)
{
  const int row0 = blockIdx.x * 64;
  const int tid = threadIdx.x, lane = tid & 63, wv = tid >> 6;
  __shared__ __attribute__((aligned(16))) short Xs[64][Hh + 8];

  const float4* src = (const float4*)(hV + (size_t)row0 * Hh);
  #pragma unroll
  for (int j = 0; j < 8; ++j){
    int idx = tid + 256*j;           // < 2048
    int r = idx >> 5, c4 = idx & 31;
    float4 v = src[idx];
    short4 s = make_short4(f2bf(v.x), f2bf(v.y), f2bf(v.z), f2bf(v.w));
    *(short4*)&Xs[r][c4*4] = s;
  }
  __syncthreads();

  const int arow = lane & 15, kgrp = (lane >> 4) * 8;
  const int col0 = wv * 32, ccol = lane & 15, crow0 = (lane >> 4) * 4;

  f32x4 acc[4][2];
  #pragma unroll
  for (int m = 0; m < 4; ++m) for (int n = 0; n < 2; ++n) acc[m][n] = (f32x4){0.f,0.f,0.f,0.f};

  const short8v* Bw = (const short8v*)w1vT;   // row stride 128/8 = 16
  #pragma unroll
  for (int ks = 0; ks < 4; ++ks){
    int kb = ks*32 + kgrp;
    short8v b0 = Bw[(col0 + arow)*16      + (kb >> 3)];
    short8v b1f = Bw[(col0 + 16 + arow)*16 + (kb >> 3)];
    #pragma unroll
    for (int m = 0; m < 4; ++m){
      short8v a = *(const short8v*)&Xs[m*16 + arow][kb];
      acc[m][0] = __builtin_amdgcn_mfma_f32_16x16x32_bf16(a, b0,  acc[m][0], 0,0,0);
      acc[m][1] = __builtin_amdgcn_mfma_f32_16x16x32_bf16(a, b1f, acc[m][1], 0,0,0);
    }
  }
  #pragma unroll
  for (int m = 0; m < 4; ++m) for (int n = 0; n < 2; ++n){
    int colg = col0 + n*16 + ccol;
    float bb = b1[colg];
    #pragma unroll
    for (int r = 0; r < 4; ++r)
      npart[(size_t)(row0 + m*16 + crow0 + r)*Hh + colg] = acc[m][n][r] + bb;
  }
}

// ---------------- per-node edge MLP + masked K-sum + residual ----------------
// LDS: Et (48x392 bf16 = 37.6KB) is reused for M1/M2 after GEMM1 reads it.
// Total ~39.9KB -> 4 blocks/CU (16 waves/CU).
__global__ __launch_bounds__(256,4) void edge_kernel(
    const float* __restrict__ hE, const float* __restrict__ hV,
    const float* __restrict__ maskA, const float* __restrict__ npart,
    const short* __restrict__ w1eT, const short* __restrict__ w2T,
    const short* __restrict__ w3T,
    const float* __restrict__ b2, const float* __restrict__ b3,
    float* __restrict__ out)
{
  const int node = blockIdx.x;
  const int tid = threadIdx.x, lane = tid & 63, wv = tid >> 6;

  __shared__ __attribute__((aligned(16))) short Et[KN][NINc + 8];
  __shared__ float msk[KN];
  __shared__ float npS[Hh], b2S[Hh], b3S[Hh], hvS[Hh];
  __shared__ float smaskSum;

  short (*M1)[Hh + 8] = (short (*)[Hh + 8])(&Et[0][0]);
  short (*M2)[Hh + 8] = (short (*)[Hh + 8])(&Et[0][0] + (size_t)KN * (Hh + 8));

  // stage h_E tile (48x384 f32 -> bf16): register-batched so 9 loads are in
  // flight before any conversion/ds_write (avoids per-iter vmcnt serialization)
  {
    const float4* src = (const float4*)(hE + (size_t)node * (KN*NINc));
    #pragma unroll
    for (int half = 0; half < 2; ++half){
      float4 v[9];
      #pragma unroll
      for (int j = 0; j < 9; ++j) v[j] = src[tid + 256*(half*9 + j)];
      #pragma unroll
      for (int j = 0; j < 9; ++j){
        int idx = tid + 256*(half*9 + j);      // < 4608
        int r = idx / 96, c4 = idx - r*96;
        *(short4*)&Et[r][c4*4] =
          make_short4(f2bf(v[j].x), f2bf(v[j].y), f2bf(v[j].z), f2bf(v[j].w));
      }
    }
  }
  if (tid < KN) msk[tid] = maskA[node*KN + tid];
  if (tid < Hh){
    npS[tid] = npart[(size_t)node*Hh + tid];
    b2S[tid] = b2[tid];
    b3S[tid] = b3[tid];
    hvS[tid] = hV[(size_t)node*Hh + tid];
  }
  __syncthreads();
  if (tid == 0){ float s = 0.f; for (int k = 0; k < KN; ++k) s += msk[k]; smaskSum = s; }

  const int arow = lane & 15, kgrp = (lane >> 4) * 8;
  const int col0 = wv * 32, ccol = lane & 15, crow0 = (lane >> 4) * 4;

  // ---- GEMM1: Et[48x384] @ W1e^T -> gelu(+node_part) -> M1 (aliases Et) ----
  {
    f32x4 acc[3][2];
    #pragma unroll
    for (int m = 0; m < 3; ++m) for (int n = 0; n < 2; ++n) acc[m][n] = (f32x4){0.f,0.f,0.f,0.f};
    const short8v* B1 = (const short8v*)w1eT;   // row stride 384/8 = 48
    #pragma unroll
    for (int ks = 0; ks < 12; ++ks){
      int kb = ks*32 + kgrp;
      short8v b0 = B1[(col0 + arow)*48      + (kb >> 3)];
      short8v b1f = B1[(col0 + 16 + arow)*48 + (kb >> 3)];
      short8v a0 = *(const short8v*)&Et[arow][kb];
      short8v a1 = *(const short8v*)&Et[16 + arow][kb];
      short8v a2 = *(const short8v*)&Et[32 + arow][kb];
      acc[0][0] = __builtin_amdgcn_mfma_f32_16x16x32_bf16(a0,b0, acc[0][0],0,0,0);
      acc[1][0] = __builtin_amdgcn_mfma_f32_16x16x32_bf16(a1,b0, acc[1][0],0,0,0);
      acc[2][0] = __builtin_amdgcn_mfma_f32_16x16x32_bf16(a2,b0, acc[2][0],0,0,0);
      acc[0][1] = __builtin_amdgcn_mfma_f32_16x16x32_bf16(a0,b1f,acc[0][1],0,0,0);
      acc[1][1] = __builtin_amdgcn_mfma_f32_16x16x32_bf16(a1,b1f,acc[1][1],0,0,0);
      acc[2][1] = __builtin_amdgcn_mfma_f32_16x16x32_bf16(a2,b1f,acc[2][1],0,0,0);
    }
    __syncthreads();   // all waves done READING Et before M1 overwrites it
    #pragma unroll
    for (int m = 0; m < 3; ++m) for (int n = 0; n < 2; ++n){
      int colg = col0 + n*16 + ccol;
      float npv = npS[colg];
      #pragma unroll
      for (int r = 0; r < 4; ++r)
        M1[m*16 + crow0 + r][colg] = f2bf(gelu_f(acc[m][n][r] + npv));
    }
  }
  __syncthreads();

  // ---- GEMM2: M1 @ W2^T -> gelu(+b2) -> M2 (aliases Et, disjoint from M1) ----
  {
    f32x4 acc[3][2];
    #pragma unroll
    for (int m = 0; m < 3; ++m) for (int n = 0; n < 2; ++n) acc[m][n] = (f32x4){0.f,0.f,0.f,0.f};
    const short8v* B2 = (const short8v*)w2T;    // row stride 16
    #pragma unroll
    for (int ks = 0; ks < 4; ++ks){
      int kb = ks*32 + kgrp;
      short8v b0 = B2[(col0 + arow)*16      + (kb >> 3)];
      short8v b1f = B2[(col0 + 16 + arow)*16 + (kb >> 3)];
      short8v a0 = *(const short8v*)&M1[arow][kb];
      short8v a1 = *(const short8v*)&M1[16 + arow][kb];
      short8v a2 = *(const short8v*)&M1[32 + arow][kb];
      acc[0][0] = __builtin_amdgcn_mfma_f32_16x16x32_bf16(a0,b0, acc[0][0],0,0,0);
      acc[1][0] = __builtin_amdgcn_mfma_f32_16x16x32_bf16(a1,b0, acc[1][0],0,0,0);
      acc[2][0] = __builtin_amdgcn_mfma_f32_16x16x32_bf16(a2,b0, acc[2][0],0,0,0);
      acc[0][1] = __builtin_amdgcn_mfma_f32_16x16x32_bf16(a0,b1f,acc[0][1],0,0,0);
      acc[1][1] = __builtin_amdgcn_mfma_f32_16x16x32_bf16(a1,b1f,acc[1][1],0,0,0);
      acc[2][1] = __builtin_amdgcn_mfma_f32_16x16x32_bf16(a2,b1f,acc[2][1],0,0,0);
    }
    __syncthreads();   // all waves done reading M1
    #pragma unroll
    for (int m = 0; m < 3; ++m) for (int n = 0; n < 2; ++n){
      int colg = col0 + n*16 + ccol;
      float bb = b2S[colg];
      #pragma unroll
      for (int r = 0; r < 4; ++r)
        M2[m*16 + crow0 + r][colg] = f2bf(gelu_f(acc[m][n][r] + bb));
    }
  }
  __syncthreads();

  // ---- GEMM3: M2 @ W3^T, then masked sum over K rows ----
  {
    f32x4 acc[3][2];
    #pragma unroll
    for (int m = 0; m < 3; ++m) for (int n = 0; n < 2; ++n) acc[m][n] = (f32x4){0.f,0.f,0.f,0.f};
    const short8v* B3 = (const short8v*)w3T;
    #pragma unroll
    for (int ks = 0; ks < 4; ++ks){
      int kb = ks*32 + kgrp;
      short8v b0 = B3[(col0 + arow)*16      + (kb >> 3)];
      short8v b1f = B3[(col0 + 16 + arow)*16 + (kb >> 3)];
      short8v a0 = *(const short8v*)&M2[arow][kb];
      short8v a1 = *(const short8v*)&M2[16 + arow][kb];
      short8v a2 = *(const short8v*)&M2[32 + arow][kb];
      acc[0][0] = __builtin_amdgcn_mfma_f32_16x16x32_bf16(a0,b0, acc[0][0],0,0,0);
      acc[1][0] = __builtin_amdgcn_mfma_f32_16x16x32_bf16(a1,b0, acc[1][0],0,0,0);
      acc[2][0] = __builtin_amdgcn_mfma_f32_16x16x32_bf16(a2,b0, acc[2][0],0,0,0);
      acc[0][1] = __builtin_amdgcn_mfma_f32_16x16x32_bf16(a0,b1f,acc[0][1],0,0,0);
      acc[1][1] = __builtin_amdgcn_mfma_f32_16x16x32_bf16(a1,b1f,acc[1][1],0,0,0);
      acc[2][1] = __builtin_amdgcn_mfma_f32_16x16x32_bf16(a2,b1f,acc[2][1],0,0,0);
    }
    // masked column sums: bias handled as b3*sum(mask); each wave owns disjoint cols
    #pragma unroll
    for (int n = 0; n < 2; ++n){
      float s = 0.f;
      #pragma unroll
      for (int m = 0; m < 3; ++m)
        #pragma unroll
        for (int r = 0; r < 4; ++r)
          s += acc[m][n][r] * msk[m*16 + crow0 + r];
      s += __shfl_xor(s, 16);
      s += __shfl_xor(s, 32);
      if (lane < 16){
        int colg = col0 + n*16 + ccol;
        float dh = (s + b3S[colg] * smaskSum) * (1.0f/30.0f);
        out[(size_t)node*Hh + colg] = hvS[colg] + dh;
      }
    }
  }
}

// ---------------- batched LN1 -> FFN -> LN2 -> mask (in-place on d_out) ----------------
__global__ __launch_bounds__(256,2) void ffn_kernel(
    const float* __restrict__ ln1g, const float* __restrict__ ln1b,
    const short* __restrict__ winT, const float* __restrict__ bin,
    const short* __restrict__ woutT, const float* __restrict__ bout,
    const float* __restrict__ ln2g, const float* __restrict__ ln2b,
    const float* __restrict__ maskV, float* __restrict__ io)
{
  const int row0 = blockIdx.x * 32;
  const int tid = threadIdx.x, lane = tid & 63, wv = tid >> 6;
  __shared__ __attribute__((aligned(16))) short Xs[32][Hh + 8];
  __shared__ __attribute__((aligned(16))) float Rs[32][Hh + 4];
  __shared__ __attribute__((aligned(16))) short Hs[32][FFd + 8];

  const int arow = lane & 15, kgrp = (lane >> 4) * 8;
  const int ccol = lane & 15, crow0 = (lane >> 4) * 4;

  // ---- LN1 (8 lanes per row) ----
  {
    int r = tid >> 3, cb = (tid & 7) * 16;
    const float4* xp = (const float4*)(io + (size_t)(row0 + r)*Hh + cb);
    float xv[16];
    #pragma unroll
    for (int j = 0; j < 4; ++j){
      float4 v = xp[j];
      xv[j*4+0]=v.x; xv[j*4+1]=v.y; xv[j*4+2]=v.z; xv[j*4+3]=v.w;
    }
    float sum = 0.f, sq = 0.f;
    #pragma unroll
    for (int j = 0; j < 16; ++j){ sum += xv[j]; sq += xv[j]*xv[j]; }
    #pragma unroll
    for (int d = 1; d < 8; d <<= 1){ sum += __shfl_xor(sum, d); sq += __shfl_xor(sq, d); }
    float mu = sum * (1.0f/128.0f);
    float var = sq * (1.0f/128.0f) - mu*mu;
    float rstd = rsqrtf(var + 1e-5f);
    #pragma unroll
    for (int j = 0; j < 16; ++j){
      int c = cb + j;
      float xn = (xv[j] - mu) * rstd * ln1g[c] + ln1b[c];
      Xs[r][c] = f2bf(xn);
      Rs[r][c] = xn;          // residual = LN1 output
    }
  }
  __syncthreads();

  // ---- GEMM-in: [32x128] @ WinT -> gelu -> Hs[32x512] ----
  {
    f32x4 acc[2][8];
    #pragma unroll
    for (int m = 0; m < 2; ++m) for (int n = 0; n < 8; ++n) acc[m][n] = (f32x4){0.f,0.f,0.f,0.f};
    const short8v* Bw = (const short8v*)winT;   // row stride 16
    #pragma unroll
    for (int ks = 0; ks < 4; ++ks){
      int kb = ks*32 + kgrp;
      short8v a0 = *(const short8v*)&Xs[arow][kb];
      short8v a1 = *(const short8v*)&Xs[16 + arow][kb];
      #pragma unroll
      for (int n = 0; n < 8; ++n){
        short8v b = Bw[(wv*128 + n*16 + arow)*16 + (kb >> 3)];
        acc[0][n] = __builtin_amdgcn_mfma_f32_16x16x32_bf16(a0,b,acc[0][n],0,0,0);
        acc[1][n] = __builtin_amdgcn_mfma_f32_16x16x32_bf16(a1,b,acc[1][n],0,0,0);
      }
    }
    #pragma unroll
    for (int m = 0; m < 2; ++m) for (int n = 0; n < 8; ++n){
      int colg = wv*128 + n*16 + ccol;
      float bb = bin[colg];
      #pragma unroll
      for (int r = 0; r < 4; ++r)
        Hs[m*16 + crow0 + r][colg] = f2bf(gelu_f(acc[m][n][r] + bb));
    }
  }
  __syncthreads();

  // ---- GEMM-out: [32x512] @ WoutT -> + bout + resid -> Rs (pre-LN2) ----
  {
    f32x4 acc[2][2];
    #pragma unroll
    for (int m = 0; m < 2; ++m) for (int n = 0; n < 2; ++n) acc[m][n] = (f32x4){0.f,0.f,0.f,0.f};
    const short8v* Bw = (const short8v*)woutT;  // row stride 512/8 = 64
    #pragma unroll
    for (int ks = 0; ks < 16; ++ks){
      int kb = ks*32 + kgrp;
      short8v a0 = *(const short8v*)&Hs[arow][kb];
      short8v a1 = *(const short8v*)&Hs[16 + arow][kb];
      short8v b0 = Bw[(wv*32 + arow)*64      + (kb >> 3)];
      short8v b1f = Bw[(wv*32 + 16 + arow)*64 + (kb >> 3)];
      acc[0][0] = __builtin_amdgcn_mfma_f32_16x16x32_bf16(a0,b0, acc[0][0],0,0,0);
      acc[1][0] = __builtin_amdgcn_mfma_f32_16x16x32_bf16(a1,b0, acc[1][0],0,0,0);
      acc[0][1] = __builtin_amdgcn_mfma_f32_16x16x32_bf16(a0,b1f,acc[0][1],0,0,0);
      acc[1][1] = __builtin_amdgcn_mfma_f32_16x16x32_bf16(a1,b1f,acc[1][1],0,0,0);
    }
    #pragma unroll
    for (int m = 0; m < 2; ++m) for (int n = 0; n < 2; ++n){
      int colg = wv*32 + n*16 + ccol;
      float bb = bout[colg];
      #pragma unroll
      for (int r = 0; r < 4; ++r){
        int rr = m*16 + crow0 + r;
        Rs[rr][colg] = Rs[rr][colg] + acc[m][n][r] + bb;
      }
    }
  }
  __syncthreads();

  // ---- LN2 + mask + store ----
  {
    int r = tid >> 3, cb = (tid & 7) * 16;
    float xv[16];
    #pragma unroll
    for (int j = 0; j < 16; ++j) xv[j] = Rs[r][cb + j];
    float sum = 0.f, sq = 0.f;
    #pragma unroll
    for (int j = 0; j < 16; ++j){ sum += xv[j]; sq += xv[j]*xv[j]; }
    #pragma unroll
    for (int d = 1; d < 8; d <<= 1){ sum += __shfl_xor(sum, d); sq += __shfl_xor(sq, d); }
    float mu = sum * (1.0f/128.0f);
    float var = sq * (1.0f/128.0f) - mu*mu;
    float rstd = rsqrtf(var + 1e-5f);
    float mv = maskV[row0 + r];
    float* op = io + (size_t)(row0 + r)*Hh + cb;
    #pragma unroll
    for (int j = 0; j < 4; ++j){
      float4 o;
      o.x = ((xv[j*4+0] - mu)*rstd*ln2g[cb+j*4+0] + ln2b[cb+j*4+0]) * mv;
      o.y = ((xv[j*4+1] - mu)*rstd*ln2g[cb+j*4+1] + ln2b[cb+j*4+1]) * mv;
      o.z = ((xv[j*4+2] - mu)*rstd*ln2g[cb+j*4+2] + ln2b[cb+j*4+2]) * mv;
      o.w = ((xv[j*4+3] - mu)*rstd*ln2g[cb+j*4+3] + ln2b[cb+j*4+3]) * mv;
      ((float4*)op)[j] = o;
    }
  }
}

extern "C" void kernel_launch(void* const* d_in, const int* in_sizes, int n_in,
                              void* d_out, int out_size, void* d_ws, size_t ws_size,
                              hipStream_t stream)
{
  const float* hV    = (const float*)d_in[0];
  const float* hE    = (const float*)d_in[1];
  const float* maskV = (const float*)d_in[2];
  const float* maskA = (const float*)d_in[3];
  const float* W1w   = (const float*)d_in[4];
  const float* W1b   = (const float*)d_in[5];
  const float* W2w   = (const float*)d_in[6];
  const float* W2b   = (const float*)d_in[7];
  const float* W3w   = (const float*)d_in[8];
  const float* W3b   = (const float*)d_in[9];
  const float* Winw  = (const float*)d_in[10];
  const float* Winb  = (const float*)d_in[11];
  const float* Woutw = (const float*)d_in[12];
  const float* Woutb = (const float*)d_in[13];
  const float* l1g   = (const float*)d_in[14];
  const float* l1b   = (const float*)d_in[15];
  const float* l2g   = (const float*)d_in[16];
  const float* l2b   = (const float*)d_in[17];

  char* ws = (char*)d_ws;
  size_t off = 0;
  float* npart = (float*)(ws + off); off += (size_t)NNODE * Hh * 4;
  short* w1vT  = (short*)(ws + off); off += 128*128*2;
  short* w1eT  = (short*)(ws + off); off += 128*384*2;
  short* w2T   = (short*)(ws + off); off += 128*128*2;
  short* w3T   = (short*)(ws + off); off += 128*128*2;
  short* winT  = (short*)(ws + off); off += 512*128*2;
  short* woutT = (short*)(ws + off); off += 128*512*2;
  if (ws_size < off) return;   // loud failure (output stays poisoned) rather than corruption

  prep_weights<<<896, 256, 0, stream>>>(W1w, W2w, W3w, Winw, Woutw,
                                        w1vT, w1eT, w2T, w3T, winT, woutT);
  np_kernel<<<NNODE/64, 256, 0, stream>>>(hV, w1vT, W1b, npart);
  edge_kernel<<<NNODE, 256, 0, stream>>>(hE, hV, maskA, npart,
                                         w1eT, w2T, w3T, W2b, W3b, (float*)d_out);
  ffn_kernel<<<NNODE/32, 256, 0, stream>>>(l1g, l1b, winT, Winb, woutT, Woutb,
                                           l2g, l2b, maskV, (float*)d_out);
}

// Round 3
// 234.378 us; speedup vs baseline: 1.2377x; 1.0693x over previous
//
#include <hip/hip_runtime.h>
#include <hip/hip_bf16.h>

#define Hh    128
#define NINc  384
#define KN    48
#define FFd   512
#define NNODE 8192
#define NPB   32      // nodes per edge block
#define EGRID (NNODE/NPB)   // 256 blocks = 1 per CU (persistent)

typedef __attribute__((ext_vector_type(8))) short short8v;
typedef __attribute__((ext_vector_type(4))) float f32x4;

__device__ __forceinline__ short f2bf(float f){
  union { float f; unsigned u; } v; v.f = f;
  unsigned r = v.u + 0x7FFFu + ((v.u >> 16) & 1u);
  return (short)(r >> 16);
}

// 0.5x(1+tanh(t)) == x*sigmoid(2t); tanh-form GELU, max dev from erf-GELU ~3e-4
__device__ __forceinline__ float gelu_f(float x){
  float t = 0.7978845608028654f * x * (1.0f + 0.044715f * x * x);
  float e = __expf(2.0f * t);           // inf-safe
  return x * (1.0f - 1.0f / (e + 1.0f));
}

// ---------------- weight prep: transpose to [out][in], convert to bf16 ----------------
__global__ void prep_weights(const float* __restrict__ W1, const float* __restrict__ W2,
                             const float* __restrict__ W3, const float* __restrict__ Win,
                             const float* __restrict__ Wout,
                             short* __restrict__ w1vT, short* __restrict__ w1eT,
                             short* __restrict__ w2T,  short* __restrict__ w3T,
                             short* __restrict__ winT, short* __restrict__ woutT)
{
  int i = blockIdx.x * 256 + threadIdx.x;
  if (i < 16384){ int n = i / 128, k = i % 128; w1vT[i] = f2bf(W1[k*128 + n]); return; }
  i -= 16384;
  if (i < 49152){ int n = i / 384, k = i % 384; w1eT[i] = f2bf(W1[(128+k)*128 + n]); return; }
  i -= 49152;
  if (i < 16384){ int n = i / 128, k = i % 128; w2T[i] = f2bf(W2[k*128 + n]); return; }
  i -= 16384;
  if (i < 16384){ int n = i / 128, k = i % 128; w3T[i] = f2bf(W3[k*128 + n]); return; }
  i -= 16384;
  if (i < 65536){ int n = i / 128, k = i % 128; winT[i] = f2bf(Win[k*512 + n]); return; }
  i -= 65536;
  if (i < 65536){ int n = i / 512, k = i % 512; woutT[i] = f2bf(Wout[k*128 + n]); return; }
}

// ---------------- node_part = h_V @ W1[:128,:] + b1  (tiny MFMA GEMM) ----------------
__global__ __launch_bounds__(256,2) void np_kernel(
    const float* __restrict__ hV, const short* __restrict__ w1vT,
    const float* __restrict__ b1, float* __restrict__ npart)
{
  const int row0 = blockIdx.x * 64;
  const int tid = threadIdx.x, lane = tid & 63, wv = tid >> 6;
  __shared__ __attribute__((aligned(16))) short Xs[64][Hh + 8];

  const float4* src = (const float4*)(hV + (size_t)row0 * Hh);
  #pragma unroll
  for (int j = 0; j < 8; ++j){
    int idx = tid + 256*j;           // < 2048
    int r = idx >> 5, c4 = idx & 31;
    float4 v = src[idx];
    short4 s = make_short4(f2bf(v.x), f2bf(v.y), f2bf(v.z), f2bf(v.w));
    *(short4*)&Xs[r][c4*4] = s;
  }
  __syncthreads();

  const int arow = lane & 15, kgrp = (lane >> 4) * 8;
  const int col0 = wv * 32, ccol = lane & 15, crow0 = (lane >> 4) * 4;

  f32x4 acc[4][2];
  #pragma unroll
  for (int m = 0; m < 4; ++m) for (int n = 0; n < 2; ++n) acc[m][n] = (f32x4){0.f,0.f,0.f,0.f};

  const short8v* Bw = (const short8v*)w1vT;   // row stride 128/8 = 16
  #pragma unroll
  for (int ks = 0; ks < 4; ++ks){
    int kb = ks*32 + kgrp;
    short8v b0 = Bw[(col0 + arow)*16      + (kb >> 3)];
    short8v b1f = Bw[(col0 + 16 + arow)*16 + (kb >> 3)];
    #pragma unroll
    for (int m = 0; m < 4; ++m){
      short8v a = *(const short8v*)&Xs[m*16 + arow][kb];
      acc[m][0] = __builtin_amdgcn_mfma_f32_16x16x32_bf16(a, b0,  acc[m][0], 0,0,0);
      acc[m][1] = __builtin_amdgcn_mfma_f32_16x16x32_bf16(a, b1f, acc[m][1], 0,0,0);
    }
  }
  #pragma unroll
  for (int m = 0; m < 4; ++m) for (int n = 0; n < 2; ++n){
    int colg = col0 + n*16 + ccol;
    float bb = b1[colg];
    #pragma unroll
    for (int r = 0; r < 4; ++r)
      npart[(size_t)(row0 + m*16 + crow0 + r)*Hh + colg] = acc[m][n][r] + bb;
  }
}

// ---------------- persistent per-CU edge MLP pipeline ----------------
// 512 thr (8 waves), 1 block/CU, 32 nodes/block.
// Weights live in registers (80 VGPR/thread); per-node vmem = prefetch only.
// Pipeline: issue node t+1 loads -> GEMM1..3 on node t (LDS/reg only) ->
// vmcnt drain at convert -> barrier. M2 aliases Et (dead after GEMM1+barrier).
__global__ __launch_bounds__(512,2) void edge_kernel(
    const float* __restrict__ hE, const float* __restrict__ hV,
    const float* __restrict__ maskA, const float* __restrict__ npart,
    const short* __restrict__ w1eT, const short* __restrict__ w2T,
    const short* __restrict__ w3T,
    const float* __restrict__ b2, const float* __restrict__ b3,
    float* __restrict__ out)
{
  const int tid = threadIdx.x, lane = tid & 63, wv = tid >> 6;   // wv 0..7
  const int base = blockIdx.x * NPB;

  __shared__ __attribute__((aligned(16))) short Et[KN][NINc + 8];  // stride 392
  __shared__ __attribute__((aligned(16))) short M1[KN][Hh + 8];    // stride 136
  __shared__ float mskS[KN];
  __shared__ float npS[Hh], hvS[Hh];

  short (*M2)[Hh + 8] = (short (*)[Hh + 8])&Et[0][0];   // aliases Et region

  const int arow = lane & 15, kgrp = (lane >> 4) * 8;
  const int ccol = lane & 15, crow0 = (lane >> 4) * 4;
  const int col0 = wv * 16;
  const int colg = col0 + ccol;

  // ---- preload this wave's weight fragments into registers (held for all nodes) ----
  short8v w1f[12], w2f[4], w3f[4];
  {
    const short8v* B1 = (const short8v*)w1eT;   // [128][384/8=48]
    const short8v* B2 = (const short8v*)w2T;    // [128][16]
    const short8v* B3 = (const short8v*)w3T;
    const int rB = col0 + arow;
    #pragma unroll
    for (int ks = 0; ks < 12; ++ks) w1f[ks] = B1[rB*48 + ((ks*32 + kgrp) >> 3)];
    #pragma unroll
    for (int ks = 0; ks < 4; ++ks){
      w2f[ks] = B2[rB*16 + ((ks*32 + kgrp) >> 3)];
      w3f[ks] = B3[rB*16 + ((ks*32 + kgrp) >> 3)];
    }
  }
  const float b2v = b2[colg];
  const float b3v = b3[colg];

  float4 pf[9];
  float  pmsk = 0.f;
  float4 phv  = {0,0,0,0}, pnp = {0,0,0,0};

  auto LOADN = [&](int nn){
    const float4* src = (const float4*)(hE + (size_t)nn * (KN*NINc));
    #pragma unroll
    for (int j = 0; j < 4; ++j){
      pf[2*j]   = src[2*tid + 1024*j];
      pf[2*j+1] = src[2*tid + 1024*j + 1];
    }
    pf[8] = src[4096 + tid];
    if (tid < KN) pmsk = maskA[nn*KN + tid];
    if (tid >= 64 && tid < 96)  phv = *(const float4*)(hV    + (size_t)nn*Hh + (tid-64)*4);
    if (tid >= 96 && tid < 128) pnp = *(const float4*)(npart + (size_t)nn*Hh + (tid-96)*4);
  };
  auto STOREN = [&](){
    #pragma unroll
    for (int j = 0; j < 4; ++j){
      int e0 = 2*tid + 1024*j;
      int r = e0 / 96, c = e0 - r*96;          // c even -> 16B-aligned write
      short8v s8;
      s8[0]=f2bf(pf[2*j].x);   s8[1]=f2bf(pf[2*j].y);
      s8[2]=f2bf(pf[2*j].z);   s8[3]=f2bf(pf[2*j].w);
      s8[4]=f2bf(pf[2*j+1].x); s8[5]=f2bf(pf[2*j+1].y);
      s8[6]=f2bf(pf[2*j+1].z); s8[7]=f2bf(pf[2*j+1].w);
      *(short8v*)&Et[r][c*4] = s8;
    }
    { int e = 4096 + tid; int r = e / 96, c = e - r*96;
      *(short4*)&Et[r][c*4] =
        make_short4(f2bf(pf[8].x), f2bf(pf[8].y), f2bf(pf[8].z), f2bf(pf[8].w)); }
    if (tid < KN) mskS[tid] = pmsk;
    if (tid >= 64 && tid < 96)  *(float4*)&hvS[(tid-64)*4] = phv;
    if (tid >= 96 && tid < 128) *(float4*)&npS[(tid-96)*4] = pnp;
  };

  // prologue: stage node base
  LOADN(base);
  STOREN();
  __syncthreads();

  for (int t = 0; t < NPB; ++t){
    const int node = base + t;
    if (t + 1 < NPB) LOADN(node + 1);    // in flight across the whole compute phase

    // ---- GEMM1: Et[48x384] @ w1f -> gelu(+np) -> M1 ----
    {
      f32x4 a1[3];
      #pragma unroll
      for (int m = 0; m < 3; ++m) a1[m] = (f32x4){0.f,0.f,0.f,0.f};
      #pragma unroll
      for (int ks = 0; ks < 12; ++ks){
        int kb = ks*32 + kgrp;
        short8v v0 = *(const short8v*)&Et[arow][kb];
        short8v v1 = *(const short8v*)&Et[16 + arow][kb];
        short8v v2 = *(const short8v*)&Et[32 + arow][kb];
        a1[0] = __builtin_amdgcn_mfma_f32_16x16x32_bf16(v0, w1f[ks], a1[0], 0,0,0);
        a1[1] = __builtin_amdgcn_mfma_f32_16x16x32_bf16(v1, w1f[ks], a1[1], 0,0,0);
        a1[2] = __builtin_amdgcn_mfma_f32_16x16x32_bf16(v2, w1f[ks], a1[2], 0,0,0);
      }
      float npv = npS[colg];
      #pragma unroll
      for (int m = 0; m < 3; ++m)
        #pragma unroll
        for (int r = 0; r < 4; ++r)
          M1[m*16 + crow0 + r][colg] = f2bf(gelu_f(a1[m][r] + npv));
    }
    __syncthreads();   // A: M1 ready; Et reads done (M2-alias region free)

    // ---- GEMM2: M1 @ w2f -> gelu(+b2) -> M2 (aliases Et) ----
    {
      f32x4 a2[3];
      #pragma unroll
      for (int m = 0; m < 3; ++m) a2[m] = (f32x4){0.f,0.f,0.f,0.f};
      #pragma unroll
      for (int ks = 0; ks < 4; ++ks){
        int kb = ks*32 + kgrp;
        short8v v0 = *(const short8v*)&M1[arow][kb];
        short8v v1 = *(const short8v*)&M1[16 + arow][kb];
        short8v v2 = *(const short8v*)&M1[32 + arow][kb];
        a2[0] = __builtin_amdgcn_mfma_f32_16x16x32_bf16(v0, w2f[ks], a2[0], 0,0,0);
        a2[1] = __builtin_amdgcn_mfma_f32_16x16x32_bf16(v1, w2f[ks], a2[1], 0,0,0);
        a2[2] = __builtin_amdgcn_mfma_f32_16x16x32_bf16(v2, w2f[ks], a2[2], 0,0,0);
      }
      #pragma unroll
      for (int m = 0; m < 3; ++m)
        #pragma unroll
        for (int r = 0; r < 4; ++r)
          M2[m*16 + crow0 + r][colg] = f2bf(gelu_f(a2[m][r] + b2v));
    }
    __syncthreads();   // B: M2 ready

    // ---- GEMM3: M2 @ w3f -> masked col-sum -> out ----
    {
      f32x4 a3[3];
      #pragma unroll
      for (int m = 0; m < 3; ++m) a3[m] = (f32x4){0.f,0.f,0.f,0.f};
      #pragma unroll
      for (int ks = 0; ks < 4; ++ks){
        int kb = ks*32 + kgrp;
        short8v v0 = *(const short8v*)&M2[arow][kb];
        short8v v1 = *(const short8v*)&M2[16 + arow][kb];
        short8v v2 = *(const short8v*)&M2[32 + arow][kb];
        a3[0] = __builtin_amdgcn_mfma_f32_16x16x32_bf16(v0, w3f[ks], a3[0], 0,0,0);
        a3[1] = __builtin_amdgcn_mfma_f32_16x16x32_bf16(v1, w3f[ks], a3[1], 0,0,0);
        a3[2] = __builtin_amdgcn_mfma_f32_16x16x32_bf16(v2, w3f[ks], a3[2], 0,0,0);
      }
      // b3 folded per element: sum_k msk_k*(acc_k + b3) == sum(msk*acc) + b3*sum(msk)
      float s = 0.f;
      #pragma unroll
      for (int m = 0; m < 3; ++m)
        #pragma unroll
        for (int r = 0; r < 4; ++r)
          s += (a3[m][r] + b3v) * mskS[m*16 + crow0 + r];
      s += __shfl_xor(s, 16);
      s += __shfl_xor(s, 32);
      if (lane < 16)
        out[(size_t)node*Hh + colg] = hvS[colg] + s * (1.0f/30.0f);
    }
    __syncthreads();   // C: M2/mskS/hvS reads done -> safe to overwrite

    if (t + 1 < NPB){
      STOREN();        // vmcnt drain happens here (prefetch had full compute to land)
      __syncthreads(); // D: Et/npS/mskS/hvS ready for next node
    }
  }
}

// ---------------- batched LN1 -> FFN -> LN2 -> mask (in-place on d_out) ----------------
__global__ __launch_bounds__(256,2) void ffn_kernel(
    const float* __restrict__ ln1g, const float* __restrict__ ln1b,
    const short* __restrict__ winT, const float* __restrict__ bin,
    const short* __restrict__ woutT, const float* __restrict__ bout,
    const float* __restrict__ ln2g, const float* __restrict__ ln2b,
    const float* __restrict__ maskV, float* __restrict__ io)
{
  const int row0 = blockIdx.x * 32;
  const int tid = threadIdx.x, lane = tid & 63, wv = tid >> 6;
  __shared__ __attribute__((aligned(16))) short Xs[32][Hh + 8];
  __shared__ __attribute__((aligned(16))) float Rs[32][Hh + 4];
  __shared__ __attribute__((aligned(16))) short Hs[32][FFd + 8];

  const int arow = lane & 15, kgrp = (lane >> 4) * 8;
  const int ccol = lane & 15, crow0 = (lane >> 4) * 4;

  // ---- LN1 (8 lanes per row) ----
  {
    int r = tid >> 3, cb = (tid & 7) * 16;
    const float4* xp = (const float4*)(io + (size_t)(row0 + r)*Hh + cb);
    float xv[16];
    #pragma unroll
    for (int j = 0; j < 4; ++j){
      float4 v = xp[j];
      xv[j*4+0]=v.x; xv[j*4+1]=v.y; xv[j*4+2]=v.z; xv[j*4+3]=v.w;
    }
    float sum = 0.f, sq = 0.f;
    #pragma unroll
    for (int j = 0; j < 16; ++j){ sum += xv[j]; sq += xv[j]*xv[j]; }
    #pragma unroll
    for (int d = 1; d < 8; d <<= 1){ sum += __shfl_xor(sum, d); sq += __shfl_xor(sq, d); }
    float mu = sum * (1.0f/128.0f);
    float var = sq * (1.0f/128.0f) - mu*mu;
    float rstd = rsqrtf(var + 1e-5f);
    #pragma unroll
    for (int j = 0; j < 16; ++j){
      int c = cb + j;
      float xn = (xv[j] - mu) * rstd * ln1g[c] + ln1b[c];
      Xs[r][c] = f2bf(xn);
      Rs[r][c] = xn;          // residual = LN1 output
    }
  }
  __syncthreads();

  // ---- GEMM-in: [32x128] @ WinT -> gelu -> Hs[32x512] ----
  {
    f32x4 acc[2][8];
    #pragma unroll
    for (int m = 0; m < 2; ++m) for (int n = 0; n < 8; ++n) acc[m][n] = (f32x4){0.f,0.f,0.f,0.f};
    const short8v* Bw = (const short8v*)winT;   // row stride 16
    #pragma unroll
    for (int ks = 0; ks < 4; ++ks){
      int kb = ks*32 + kgrp;
      short8v a0 = *(const short8v*)&Xs[arow][kb];
      short8v a1 = *(const short8v*)&Xs[16 + arow][kb];
      #pragma unroll
      for (int n = 0; n < 8; ++n){
        short8v b = Bw[(wv*128 + n*16 + arow)*16 + (kb >> 3)];
        acc[0][n] = __builtin_amdgcn_mfma_f32_16x16x32_bf16(a0,b,acc[0][n],0,0,0);
        acc[1][n] = __builtin_amdgcn_mfma_f32_16x16x32_bf16(a1,b,acc[1][n],0,0,0);
      }
    }
    #pragma unroll
    for (int m = 0; m < 2; ++m) for (int n = 0; n < 8; ++n){
      int colg = wv*128 + n*16 + ccol;
      float bb = bin[colg];
      #pragma unroll
      for (int r = 0; r < 4; ++r)
        Hs[m*16 + crow0 + r][colg] = f2bf(gelu_f(acc[m][n][r] + bb));
    }
  }
  __syncthreads();

  // ---- GEMM-out: [32x512] @ WoutT -> + bout + resid -> Rs (pre-LN2) ----
  {
    f32x4 acc[2][2];
    #pragma unroll
    for (int m = 0; m < 2; ++m) for (int n = 0; n < 2; ++n) acc[m][n] = (f32x4){0.f,0.f,0.f,0.f};
    const short8v* Bw = (const short8v*)woutT;  // row stride 512/8 = 64
    #pragma unroll
    for (int ks = 0; ks < 16; ++ks){
      int kb = ks*32 + kgrp;
      short8v a0 = *(const short8v*)&Hs[arow][kb];
      short8v a1 = *(const short8v*)&Hs[16 + arow][kb];
      short8v b0 = Bw[(wv*32 + arow)*64      + (kb >> 3)];
      short8v b1f = Bw[(wv*32 + 16 + arow)*64 + (kb >> 3)];
      acc[0][0] = __builtin_amdgcn_mfma_f32_16x16x32_bf16(a0,b0, acc[0][0],0,0,0);
      acc[1][0] = __builtin_amdgcn_mfma_f32_16x16x32_bf16(a1,b0, acc[1][0],0,0,0);
      acc[0][1] = __builtin_amdgcn_mfma_f32_16x16x32_bf16(a0,b1f,acc[0][1],0,0,0);
      acc[1][1] = __builtin_amdgcn_mfma_f32_16x16x32_bf16(a1,b1f,acc[1][1],0,0,0);
    }
    #pragma unroll
    for (int m = 0; m < 2; ++m) for (int n = 0; n < 2; ++n){
      int colg = wv*32 + n*16 + ccol;
      float bb = bout[colg];
      #pragma unroll
      for (int r = 0; r < 4; ++r){
        int rr = m*16 + crow0 + r;
        Rs[rr][colg] = Rs[rr][colg] + acc[m][n][r] + bb;
      }
    }
  }
  __syncthreads();

  // ---- LN2 + mask + store ----
  {
    int r = tid >> 3, cb = (tid & 7) * 16;
    float xv[16];
    #pragma unroll
    for (int j = 0; j < 16; ++j) xv[j] = Rs[r][cb + j];
    float sum = 0.f, sq = 0.f;
    #pragma unroll
    for (int j = 0; j < 16; ++j){ sum += xv[j]; sq += xv[j]*xv[j]; }
    #pragma unroll
    for (int d = 1; d < 8; d <<= 1){ sum += __shfl_xor(sum, d); sq += __shfl_xor(sq, d); }
    float mu = sum * (1.0f/128.0f);
    float var = sq * (1.0f/128.0f) - mu*mu;
    float rstd = rsqrtf(var + 1e-5f);
    float mv = maskV[row0 + r];
    float* op = io + (size_t)(row0 + r)*Hh + cb;
    #pragma unroll
    for (int j = 0; j < 4; ++j){
      float4 o;
      o.x = ((xv[j*4+0] - mu)*rstd*ln2g[cb+j*4+0] + ln2b[cb+j*4+0]) * mv;
      o.y = ((xv[j*4+1] - mu)*rstd*ln2g[cb+j*4+1] + ln2b[cb+j*4+1]) * mv;
      o.z = ((xv[j*4+2] - mu)*rstd*ln2g[cb+j*4+2] + ln2b[cb+j*4+2]) * mv;
      o.w = ((xv[j*4+3] - mu)*rstd*ln2g[cb+j*4+3] + ln2b[cb+j*4+3]) * mv;
      ((float4*)op)[j] = o;
    }
  }
}

extern "C" void kernel_launch(void* const* d_in, const int* in_sizes, int n_in,
                              void* d_out, int out_size, void* d_ws, size_t ws_size,
                              hipStream_t stream)
{
  const float* hV    = (const float*)d_in[0];
  const float* hE    = (const float*)d_in[1];
  const float* maskV = (const float*)d_in[2];
  const float* maskA = (const float*)d_in[3];
  const float* W1w   = (const float*)d_in[4];
  const float* W1b   = (const float*)d_in[5];
  const float* W2w   = (const float*)d_in[6];
  const float* W2b   = (const float*)d_in[7];
  const float* W3w   = (const float*)d_in[8];
  const float* W3b   = (const float*)d_in[9];
  const float* Winw  = (const float*)d_in[10];
  const float* Winb  = (const float*)d_in[11];
  const float* Woutw = (const float*)d_in[12];
  const float* Woutb = (const float*)d_in[13];
  const float* l1g   = (const float*)d_in[14];
  const float* l1b   = (const float*)d_in[15];
  const float* l2g   = (const float*)d_in[16];
  const float* l2b   = (const float*)d_in[17];

  char* ws = (char*)d_ws;
  size_t off = 0;
  float* npart = (float*)(ws + off); off += (size_t)NNODE * Hh * 4;
  short* w1vT  = (short*)(ws + off); off += 128*128*2;
  short* w1eT  = (short*)(ws + off); off += 128*384*2;
  short* w2T   = (short*)(ws + off); off += 128*128*2;
  short* w3T   = (short*)(ws + off); off += 128*128*2;
  short* winT  = (short*)(ws + off); off += 512*128*2;
  short* woutT = (short*)(ws + off); off += 128*512*2;
  if (ws_size < off) return;   // loud failure (output stays poisoned) rather than corruption

  prep_weights<<<896, 256, 0, stream>>>(W1w, W2w, W3w, Winw, Woutw,
                                        w1vT, w1eT, w2T, w3T, winT, woutT);
  np_kernel<<<NNODE/64, 256, 0, stream>>>(hV, w1vT, W1b, npart);
  edge_kernel<<<EGRID, 512, 0, stream>>>(hE, hV, maskA, npart,
                                         w1eT, w2T, w3T, W2b, W3b, (float*)d_out);
  ffn_kernel<<<NNODE/32, 256, 0, stream>>>(l1g, l1b, winT, Winb, woutT, Woutb,
                                           l2g, l2b, maskV, (float*)d_out);
}

// Round 4
// 225.573 us; speedup vs baseline: 1.2860x; 1.0390x over previous
//
#include <hip/hip_runtime.h>
#include <hip/hip_bf16.h>

#define Hh    128
#define NINc  384
#define KN    48
#define FFd   512
#define NNODE 8192
#define NPB   32            // nodes per edge block
#define EGRID (NNODE/NPB)   // 256 blocks = 1 per CU (persistent)

typedef __attribute__((ext_vector_type(8))) short short8v;
typedef __attribute__((ext_vector_type(4))) float f32x4;

// hardware RNE conversion (v_cvt_pk_bf16_f32)
__device__ __forceinline__ short f2bf1(float f){
  union { __hip_bfloat16 h; short s; } c; c.h = __float2bfloat16(f);
  return c.s;
}
__device__ __forceinline__ unsigned pk_bf16(float lo, float hi){
  union { __hip_bfloat162 h; unsigned u; } c;
  c.h = __float22bfloat162_rn(make_float2(lo, hi));
  return c.u;
}

// 0.5x(1+tanh(t)) == x*sigmoid(2t); tanh-form GELU, max dev from erf-GELU ~3e-4
__device__ __forceinline__ float gelu_f(float x){
  float t = 0.7978845608028654f * x * (1.0f + 0.044715f * x * x);
  float e = __expf(2.0f * t);           // inf-safe
  return x * (1.0f - 1.0f / (e + 1.0f));
}

// LDS-publish barrier WITHOUT vmem drain (the whole point: prefetch loads
// stay in flight across s_barrier; __syncthreads would s_waitcnt vmcnt(0))
__device__ __forceinline__ void bar_lds(){
  asm volatile("s_waitcnt lgkmcnt(0)\n\ts_barrier" ::: "memory");
}

// ---------------- weight prep: transpose to [out][in], convert to bf16 ----------------
__global__ void prep_weights(const float* __restrict__ W1, const float* __restrict__ W2,
                             const float* __restrict__ W3, const float* __restrict__ Win,
                             const float* __restrict__ Wout,
                             short* __restrict__ w1vT, short* __restrict__ w1eT,
                             short* __restrict__ w2T,  short* __restrict__ w3T,
                             short* __restrict__ winT, short* __restrict__ woutT)
{
  int i = blockIdx.x * 256 + threadIdx.x;
  if (i < 16384){ int n = i / 128, k = i % 128; w1vT[i] = f2bf1(W1[k*128 + n]); return; }
  i -= 16384;
  if (i < 49152){ int n = i / 384, k = i % 384; w1eT[i] = f2bf1(W1[(128+k)*128 + n]); return; }
  i -= 49152;
  if (i < 16384){ int n = i / 128, k = i % 128; w2T[i] = f2bf1(W2[k*128 + n]); return; }
  i -= 16384;
  if (i < 16384){ int n = i / 128, k = i % 128; w3T[i] = f2bf1(W3[k*128 + n]); return; }
  i -= 16384;
  if (i < 65536){ int n = i / 128, k = i % 128; winT[i] = f2bf1(Win[k*512 + n]); return; }
  i -= 65536;
  if (i < 65536){ int n = i / 512, k = i % 512; woutT[i] = f2bf1(Wout[k*128 + n]); return; }
}

// ---------------- node_part = h_V @ W1[:128,:] + b1  (tiny MFMA GEMM) ----------------
__global__ __launch_bounds__(256,2) void np_kernel(
    const float* __restrict__ hV, const short* __restrict__ w1vT,
    const float* __restrict__ b1, float* __restrict__ npart)
{
  const int row0 = blockIdx.x * 64;
  const int tid = threadIdx.x, lane = tid & 63, wv = tid >> 6;
  __shared__ __attribute__((aligned(16))) short Xs[64][Hh + 8];

  const float4* src = (const float4*)(hV + (size_t)row0 * Hh);
  #pragma unroll
  for (int j = 0; j < 8; ++j){
    int idx = tid + 256*j;           // < 2048
    int r = idx >> 5, c4 = idx & 31;
    float4 v = src[idx];
    unsigned u0 = pk_bf16(v.x, v.y), u1 = pk_bf16(v.z, v.w);
    *(uint2*)&Xs[r][c4*4] = make_uint2(u0, u1);
  }
  __syncthreads();

  const int arow = lane & 15, kgrp = (lane >> 4) * 8;
  const int col0 = wv * 32, ccol = lane & 15, crow0 = (lane >> 4) * 4;

  f32x4 acc[4][2];
  #pragma unroll
  for (int m = 0; m < 4; ++m) for (int n = 0; n < 2; ++n) acc[m][n] = (f32x4){0.f,0.f,0.f,0.f};

  const short8v* Bw = (const short8v*)w1vT;   // row stride 128/8 = 16
  #pragma unroll
  for (int ks = 0; ks < 4; ++ks){
    int kb = ks*32 + kgrp;
    short8v b0 = Bw[(col0 + arow)*16      + (kb >> 3)];
    short8v b1f = Bw[(col0 + 16 + arow)*16 + (kb >> 3)];
    #pragma unroll
    for (int m = 0; m < 4; ++m){
      short8v a = *(const short8v*)&Xs[m*16 + arow][kb];
      acc[m][0] = __builtin_amdgcn_mfma_f32_16x16x32_bf16(a, b0,  acc[m][0], 0,0,0);
      acc[m][1] = __builtin_amdgcn_mfma_f32_16x16x32_bf16(a, b1f, acc[m][1], 0,0,0);
    }
  }
  #pragma unroll
  for (int m = 0; m < 4; ++m) for (int n = 0; n < 2; ++n){
    int colg = col0 + n*16 + ccol;
    float bb = b1[colg];
    #pragma unroll
    for (int r = 0; r < 4; ++r)
      npart[(size_t)(row0 + m*16 + crow0 + r)*Hh + colg] = acc[m][n][r] + bb;
  }
}

// ---------------- persistent per-CU edge MLP pipeline ----------------
// 512 thr (8 waves), 1 block/CU, 32 nodes/block. Weights in registers.
// Double-buffered Et/np/msk/hv; 3 lgkm-only barriers per node; the ONLY
// vmem wait is the compiler's counted wait on pf[] at STOREN (3 GEMM
// phases after issue) -> HBM queue stays full across the whole iteration.
__global__ __launch_bounds__(512,2) void edge_kernel(
    const float* __restrict__ hE, const float* __restrict__ hV,
    const float* __restrict__ maskA, const float* __restrict__ npart,
    const short* __restrict__ w1eT, const short* __restrict__ w2T,
    const short* __restrict__ w3T,
    const float* __restrict__ b2, const float* __restrict__ b3,
    float* __restrict__ out)
{
  const int tid = threadIdx.x, lane = tid & 63, wv = tid >> 6;   // wv 0..7
  const int base = blockIdx.x * NPB;

  __shared__ __attribute__((aligned(16))) short Etd[2][KN][NINc + 8]; // 2x37.6KB
  __shared__ __attribute__((aligned(16))) short M1[KN][Hh + 8];
  __shared__ __attribute__((aligned(16))) short M2[KN][Hh + 8];
  __shared__ float mskS[2][KN];
  __shared__ float npS[2][Hh], hvS[2][Hh];

  const int arow = lane & 15, kgrp = (lane >> 4) * 8;
  const int ccol = lane & 15, crow0 = (lane >> 4) * 4;
  const int col0 = wv * 16;
  const int colg = col0 + ccol;

  // ---- preload this wave's weight fragments into registers (held for all nodes) ----
  short8v w1f[12], w2f[4], w3f[4];
  {
    const short8v* B1 = (const short8v*)w1eT;   // [128][48]
    const short8v* B2 = (const short8v*)w2T;    // [128][16]
    const short8v* B3 = (const short8v*)w3T;
    const int rB = col0 + arow;
    #pragma unroll
    for (int ks = 0; ks < 12; ++ks) w1f[ks] = B1[rB*48 + ((ks*32 + kgrp) >> 3)];
    #pragma unroll
    for (int ks = 0; ks < 4; ++ks){
      w2f[ks] = B2[rB*16 + ((ks*32 + kgrp) >> 3)];
      w3f[ks] = B3[rB*16 + ((ks*32 + kgrp) >> 3)];
    }
  }
  const float b2v = b2[colg];
  const float b3v = b3[colg];

  float4 pf[9];
  float  pmsk = 0.f;
  float4 phv  = {0,0,0,0}, pnp = {0,0,0,0};

  auto LOADN = [&](int nn){
    const float4* src = (const float4*)(hE + (size_t)nn * (KN*NINc));
    #pragma unroll
    for (int j = 0; j < 4; ++j){
      pf[2*j]   = src[2*tid + 1024*j];
      pf[2*j+1] = src[2*tid + 1024*j + 1];
    }
    pf[8] = src[4096 + tid];
    if (tid < KN) pmsk = maskA[nn*KN + tid];
    if (tid >= 64 && tid < 96)  phv = *(const float4*)(hV    + (size_t)nn*Hh + (tid-64)*4);
    if (tid >= 96 && tid < 128) pnp = *(const float4*)(npart + (size_t)nn*Hh + (tid-96)*4);
  };
  auto STOREN = [&](int buf){
    #pragma unroll
    for (int j = 0; j < 4; ++j){
      int e0 = 2*tid + 1024*j;
      int r = e0 / 96, c = e0 - r*96;          // c even -> 16B-aligned write
      uint4 u;
      u.x = pk_bf16(pf[2*j].x,   pf[2*j].y);
      u.y = pk_bf16(pf[2*j].z,   pf[2*j].w);
      u.z = pk_bf16(pf[2*j+1].x, pf[2*j+1].y);
      u.w = pk_bf16(pf[2*j+1].z, pf[2*j+1].w);
      *(uint4*)&Etd[buf][r][c*4] = u;
    }
    { int e = 4096 + tid; int r = e / 96, c = e - r*96;
      *(uint2*)&Etd[buf][r][c*4] =
        make_uint2(pk_bf16(pf[8].x, pf[8].y), pk_bf16(pf[8].z, pf[8].w)); }
    if (tid < KN) mskS[buf][tid] = pmsk;
    if (tid >= 64 && tid < 96)  *(float4*)&hvS[buf][(tid-64)*4] = phv;
    if (tid >= 96 && tid < 128) *(float4*)&npS[buf][(tid-96)*4] = pnp;
  };

  // prologue: stage node base into buffer 0
  LOADN(base);
  STOREN(0);
  bar_lds();

  int cur = 0;
  for (int t = 0; t < NPB; ++t){
    const int node = base + t;
    if (t + 1 < NPB) LOADN(node + 1);    // issued now, waited at STOREN below

    // ---- GEMM1: Etd[cur][48x384] @ w1f -> gelu(+np) -> M1 ----
    {
      f32x4 a1[3];
      #pragma unroll
      for (int m = 0; m < 3; ++m) a1[m] = (f32x4){0.f,0.f,0.f,0.f};
      #pragma unroll
      for (int ks = 0; ks < 12; ++ks){
        int kb = ks*32 + kgrp;
        short8v v0 = *(const short8v*)&Etd[cur][arow][kb];
        short8v v1 = *(const short8v*)&Etd[cur][16 + arow][kb];
        short8v v2 = *(const short8v*)&Etd[cur][32 + arow][kb];
        a1[0] = __builtin_amdgcn_mfma_f32_16x16x32_bf16(v0, w1f[ks], a1[0], 0,0,0);
        a1[1] = __builtin_amdgcn_mfma_f32_16x16x32_bf16(v1, w1f[ks], a1[1], 0,0,0);
        a1[2] = __builtin_amdgcn_mfma_f32_16x16x32_bf16(v2, w1f[ks], a1[2], 0,0,0);
      }
      float npv = npS[cur][colg];
      #pragma unroll
      for (int m = 0; m < 3; ++m)
        #pragma unroll
        for (int r = 0; r < 4; ++r)
          M1[m*16 + crow0 + r][colg] = f2bf1(gelu_f(a1[m][r] + npv));
    }
    bar_lds();   // A: M1 visible

    // ---- GEMM2: M1 @ w2f -> gelu(+b2) -> M2 ----
    {
      f32x4 a2[3];
      #pragma unroll
      for (int m = 0; m < 3; ++m) a2[m] = (f32x4){0.f,0.f,0.f,0.f};
      #pragma unroll
      for (int ks = 0; ks < 4; ++ks){
        int kb = ks*32 + kgrp;
        short8v v0 = *(const short8v*)&M1[arow][kb];
        short8v v1 = *(const short8v*)&M1[16 + arow][kb];
        short8v v2 = *(const short8v*)&M1[32 + arow][kb];
        a2[0] = __builtin_amdgcn_mfma_f32_16x16x32_bf16(v0, w2f[ks], a2[0], 0,0,0);
        a2[1] = __builtin_amdgcn_mfma_f32_16x16x32_bf16(v1, w2f[ks], a2[1], 0,0,0);
        a2[2] = __builtin_amdgcn_mfma_f32_16x16x32_bf16(v2, w2f[ks], a2[2], 0,0,0);
      }
      #pragma unroll
      for (int m = 0; m < 3; ++m)
        #pragma unroll
        for (int r = 0; r < 4; ++r)
          M2[m*16 + crow0 + r][colg] = f2bf1(gelu_f(a2[m][r] + b2v));
    }
    bar_lds();   // B: M2 visible

    // ---- GEMM3: M2 @ w3f -> masked col-sum -> out ----
    {
      f32x4 a3[3];
      #pragma unroll
      for (int m = 0; m < 3; ++m) a3[m] = (f32x4){0.f,0.f,0.f,0.f};
      #pragma unroll
      for (int ks = 0; ks < 4; ++ks){
        int kb = ks*32 + kgrp;
        short8v v0 = *(const short8v*)&M2[arow][kb];
        short8v v1 = *(const short8v*)&M2[16 + arow][kb];
        short8v v2 = *(const short8v*)&M2[32 + arow][kb];
        a3[0] = __builtin_amdgcn_mfma_f32_16x16x32_bf16(v0, w3f[ks], a3[0], 0,0,0);
        a3[1] = __builtin_amdgcn_mfma_f32_16x16x32_bf16(v1, w3f[ks], a3[1], 0,0,0);
        a3[2] = __builtin_amdgcn_mfma_f32_16x16x32_bf16(v2, w3f[ks], a3[2], 0,0,0);
      }
      // b3 folded per element: sum_k msk_k*(acc_k + b3)
      float s = 0.f;
      #pragma unroll
      for (int m = 0; m < 3; ++m)
        #pragma unroll
        for (int r = 0; r < 4; ++r)
          s += (a3[m][r] + b3v) * mskS[cur][m*16 + crow0 + r];
      s += __shfl_xor(s, 16);
      s += __shfl_xor(s, 32);
      if (lane < 16)
        out[(size_t)node*Hh + colg] = hvS[cur][colg] + s * (1.0f/30.0f);
    }

    // no barrier needed before STOREN: it writes the OTHER buffer set,
    // disjoint from everything GEMM3 stragglers read (M2/mskS[cur]/hvS[cur])
    if (t + 1 < NPB){
      STOREN(cur ^ 1);   // counted vmcnt waits on pf happen here
      bar_lds();         // E: next buffers visible
    }
    cur ^= 1;
  }
}

// ---------------- batched LN1 -> FFN -> LN2 -> mask (in-place on d_out) ----------------
__global__ __launch_bounds__(256,2) void ffn_kernel(
    const float* __restrict__ ln1g, const float* __restrict__ ln1b,
    const short* __restrict__ winT, const float* __restrict__ bin,
    const short* __restrict__ woutT, const float* __restrict__ bout,
    const float* __restrict__ ln2g, const float* __restrict__ ln2b,
    const float* __restrict__ maskV, float* __restrict__ io)
{
  const int row0 = blockIdx.x * 32;
  const int tid = threadIdx.x, lane = tid & 63, wv = tid >> 6;
  __shared__ __attribute__((aligned(16))) short Xs[32][Hh + 8];
  __shared__ __attribute__((aligned(16))) float Rs[32][Hh + 4];
  __shared__ __attribute__((aligned(16))) short Hs[32][FFd + 8];

  const int arow = lane & 15, kgrp = (lane >> 4) * 8;
  const int ccol = lane & 15, crow0 = (lane >> 4) * 4;

  // ---- LN1 (8 lanes per row) ----
  {
    int r = tid >> 3, cb = (tid & 7) * 16;
    const float4* xp = (const float4*)(io + (size_t)(row0 + r)*Hh + cb);
    float xv[16];
    #pragma unroll
    for (int j = 0; j < 4; ++j){
      float4 v = xp[j];
      xv[j*4+0]=v.x; xv[j*4+1]=v.y; xv[j*4+2]=v.z; xv[j*4+3]=v.w;
    }
    float sum = 0.f, sq = 0.f;
    #pragma unroll
    for (int j = 0; j < 16; ++j){ sum += xv[j]; sq += xv[j]*xv[j]; }
    #pragma unroll
    for (int d = 1; d < 8; d <<= 1){ sum += __shfl_xor(sum, d); sq += __shfl_xor(sq, d); }
    float mu = sum * (1.0f/128.0f);
    float var = sq * (1.0f/128.0f) - mu*mu;
    float rstd = rsqrtf(var + 1e-5f);
    #pragma unroll
    for (int j = 0; j < 16; ++j){
      int c = cb + j;
      float xn = (xv[j] - mu) * rstd * ln1g[c] + ln1b[c];
      Xs[r][c] = f2bf1(xn);
      Rs[r][c] = xn;          // residual = LN1 output
    }
  }
  __syncthreads();

  // ---- GEMM-in: [32x128] @ WinT -> gelu -> Hs[32x512] ----
  {
    f32x4 acc[2][8];
    #pragma unroll
    for (int m = 0; m < 2; ++m) for (int n = 0; n < 8; ++n) acc[m][n] = (f32x4){0.f,0.f,0.f,0.f};
    const short8v* Bw = (const short8v*)winT;   // row stride 16
    #pragma unroll
    for (int ks = 0; ks < 4; ++ks){
      int kb = ks*32 + kgrp;
      short8v a0 = *(const short8v*)&Xs[arow][kb];
      short8v a1 = *(const short8v*)&Xs[16 + arow][kb];
      #pragma unroll
      for (int n = 0; n < 8; ++n){
        short8v b = Bw[(wv*128 + n*16 + arow)*16 + (kb >> 3)];
        acc[0][n] = __builtin_amdgcn_mfma_f32_16x16x32_bf16(a0,b,acc[0][n],0,0,0);
        acc[1][n] = __builtin_amdgcn_mfma_f32_16x16x32_bf16(a1,b,acc[1][n],0,0,0);
      }
    }
    #pragma unroll
    for (int m = 0; m < 2; ++m) for (int n = 0; n < 8; ++n){
      int colg = wv*128 + n*16 + ccol;
      float bb = bin[colg];
      #pragma unroll
      for (int r = 0; r < 4; ++r)
        Hs[m*16 + crow0 + r][colg] = f2bf1(gelu_f(acc[m][n][r] + bb));
    }
  }
  __syncthreads();

  // ---- GEMM-out: [32x512] @ WoutT -> + bout + resid -> Rs (pre-LN2) ----
  {
    f32x4 acc[2][2];
    #pragma unroll
    for (int m = 0; m < 2; ++m) for (int n = 0; n < 2; ++n) acc[m][n] = (f32x4){0.f,0.f,0.f,0.f};
    const short8v* Bw = (const short8v*)woutT;  // row stride 512/8 = 64
    #pragma unroll
    for (int ks = 0; ks < 16; ++ks){
      int kb = ks*32 + kgrp;
      short8v a0 = *(const short8v*)&Hs[arow][kb];
      short8v a1 = *(const short8v*)&Hs[16 + arow][kb];
      short8v b0 = Bw[(wv*32 + arow)*64      + (kb >> 3)];
      short8v b1f = Bw[(wv*32 + 16 + arow)*64 + (kb >> 3)];
      acc[0][0] = __builtin_amdgcn_mfma_f32_16x16x32_bf16(a0,b0, acc[0][0],0,0,0);
      acc[1][0] = __builtin_amdgcn_mfma_f32_16x16x32_bf16(a1,b0, acc[1][0],0,0,0);
      acc[0][1] = __builtin_amdgcn_mfma_f32_16x16x32_bf16(a0,b1f,acc[0][1],0,0,0);
      acc[1][1] = __builtin_amdgcn_mfma_f32_16x16x32_bf16(a1,b1f,acc[1][1],0,0,0);
    }
    #pragma unroll
    for (int m = 0; m < 2; ++m) for (int n = 0; n < 2; ++n){
      int colg = wv*32 + n*16 + ccol;
      float bb = bout[colg];
      #pragma unroll
      for (int r = 0; r < 4; ++r){
        int rr = m*16 + crow0 + r;
        Rs[rr][colg] = Rs[rr][colg] + acc[m][n][r] + bb;
      }
    }
  }
  __syncthreads();

  // ---- LN2 + mask + store ----
  {
    int r = tid >> 3, cb = (tid & 7) * 16;
    float xv[16];
    #pragma unroll
    for (int j = 0; j < 16; ++j) xv[j] = Rs[r][cb + j];
    float sum = 0.f, sq = 0.f;
    #pragma unroll
    for (int j = 0; j < 16; ++j){ sum += xv[j]; sq += xv[j]*xv[j]; }
    #pragma unroll
    for (int d = 1; d < 8; d <<= 1){ sum += __shfl_xor(sum, d); sq += __shfl_xor(sq, d); }
    float mu = sum * (1.0f/128.0f);
    float var = sq * (1.0f/128.0f) - mu*mu;
    float rstd = rsqrtf(var + 1e-5f);
    float mv = maskV[row0 + r];
    float* op = io + (size_t)(row0 + r)*Hh + cb;
    #pragma unroll
    for (int j = 0; j < 4; ++j){
      float4 o;
      o.x = ((xv[j*4+0] - mu)*rstd*ln2g[cb+j*4+0] + ln2b[cb+j*4+0]) * mv;
      o.y = ((xv[j*4+1] - mu)*rstd*ln2g[cb+j*4+1] + ln2b[cb+j*4+1]) * mv;
      o.z = ((xv[j*4+2] - mu)*rstd*ln2g[cb+j*4+2] + ln2b[cb+j*4+2]) * mv;
      o.w = ((xv[j*4+3] - mu)*rstd*ln2g[cb+j*4+3] + ln2b[cb+j*4+3]) * mv;
      ((float4*)op)[j] = o;
    }
  }
}

extern "C" void kernel_launch(void* const* d_in, const int* in_sizes, int n_in,
                              void* d_out, int out_size, void* d_ws, size_t ws_size,
                              hipStream_t stream)
{
  const float* hV    = (const float*)d_in[0];
  const float* hE    = (const float*)d_in[1];
  const float* maskV = (const float*)d_in[2];
  const float* maskA = (const float*)d_in[3];
  const float* W1w   = (const float*)d_in[4];
  const float* W1b   = (const float*)d_in[5];
  const float* W2w   = (const float*)d_in[6];
  const float* W2b   = (const float*)d_in[7];
  const float* W3w   = (const float*)d_in[8];
  const float* W3b   = (const float*)d_in[9];
  const float* Winw  = (const float*)d_in[10];
  const float* Winb  = (const float*)d_in[11];
  const float* Woutw = (const float*)d_in[12];
  const float* Woutb = (const float*)d_in[13];
  const float* l1g   = (const float*)d_in[14];
  const float* l1b   = (const float*)d_in[15];
  const float* l2g   = (const float*)d_in[16];
  const float* l2b   = (const float*)d_in[17];

  char* ws = (char*)d_ws;
  size_t off = 0;
  float* npart = (float*)(ws + off); off += (size_t)NNODE * Hh * 4;
  short* w1vT  = (short*)(ws + off); off += 128*128*2;
  short* w1eT  = (short*)(ws + off); off += 128*384*2;
  short* w2T   = (short*)(ws + off); off += 128*128*2;
  short* w3T   = (short*)(ws + off); off += 128*128*2;
  short* winT  = (short*)(ws + off); off += 512*128*2;
  short* woutT = (short*)(ws + off); off += 128*512*2;
  if (ws_size < off) return;   // loud failure (output stays poisoned) rather than corruption

  prep_weights<<<896, 256, 0, stream>>>(W1w, W2w, W3w, Winw, Woutw,
                                        w1vT, w1eT, w2T, w3T, winT, woutT);
  np_kernel<<<NNODE/64, 256, 0, stream>>>(hV, w1vT, W1b, npart);
  edge_kernel<<<EGRID, 512, 0, stream>>>(hE, hV, maskA, npart,
                                         w1eT, w2T, w3T, W2b, W3b, (float*)d_out);
  ffn_kernel<<<NNODE/32, 256, 0, stream>>>(l1g, l1b, winT, Winb, woutT, Woutb,
                                           l2g, l2b, maskV, (float*)d_out);
}